// Round 10
// baseline (268.079 us; speedup 1.0000x reference)
//
#include <hip/hip_runtime.h>

typedef _Float16 half8 __attribute__((ext_vector_type(8)));
typedef float floatx4 __attribute__((ext_vector_type(4)));
typedef int intx4 __attribute__((ext_vector_type(4)));

#define MFMA16(a, b, c) __builtin_amdgcn_mfma_f32_16x16x32_f16(a, b, c, 0, 0, 0)

static __device__ __forceinline__ half8 asH8(intx4 v) {
  half8 r;
  __builtin_memcpy(&r, &v, 16);
  return r;
}

static constexpr int kD = 576;
// ws layout (f16 elements):
//   WS1 (GEMM1 B): [m:512] rows of 1152 f16 (2304B): per kt (18): [hi 32 f16 | lo 32 f16]
//   WS2 (GEMM2 B, hi only): [d:576][m:512] -> 1024 B/row
static constexpr int WS2 = 589824;
// total ws: 884736 f16 = 1,769,472 bytes

__global__ void prep_split(const float* __restrict__ mem, _Float16* __restrict__ ws) {
  const int m = blockIdx.x;   // 512
  const int d = threadIdx.x;  // 576
  float v = mem[m * kD + d];
  _Float16 hi = (_Float16)v;
  _Float16 lo = (_Float16)(v - (float)hi);
  const int kt = d >> 5, koct = (d >> 3) & 3, j = d & 7;
  ws[m * 1152 + kt * 64 + koct * 8 + j] = hi;
  ws[m * 1152 + kt * 64 + koct * 8 + j + 32] = lo;
  ws[WS2 + d * 512 + m] = hi;
}

// per-lane 16B global load straight to VGPR (asm: invisible to scheduler sinking)
#define GLD16A(dst, voff, OFF)                                          \
  asm volatile("global_load_dwordx4 %0, %1, %2 offset:" #OFF            \
               : "=v"(dst)                                              \
               : "v"(voff), "s"(wsp))
#define VMW_I(N)                                          \
  do {                                                    \
    asm volatile("s_waitcnt vmcnt(" #N ")" ::: "memory"); \
    __builtin_amdgcn_sched_barrier(0);                    \
  } while (0)
#define VMW(N) VMW_I(N)

// One block: 64 pixels = one (b,h) row. 512 threads / 8 waves. 1 block/CU.
// Wave-decoupled: B operands loaded per-lane direct to VGPR rings (G1 depth-3,
// G2 depth-4), counted vmcnt, NO barriers inside either GEMM loop.
__global__ __launch_bounds__(512, 2) void mem_branch_kernel(
    const float* __restrict__ x, const float* __restrict__ temperature,
    const _Float16* __restrict__ ws, float* __restrict__ out) {
  // A-frags (G1): [72 combos (kt*4+pt)][64 lanes][8 f16] = 73,728 B.
  // Reused for att-frags (G2): [64 combos (kt2*4+pt)][64][8] = 65,536 B.
  __shared__ __align__(16) _Float16 afrag[36864];
  __shared__ __align__(16) int tab[kD];
  __shared__ float redm[512];
  __shared__ float reds[512];

  const int tid = threadIdx.x;
  const int lane = tid & 63;
  const int wv = tid >> 6;  // 0..7
  const int l15 = lane & 15;
  const int koct = lane >> 4;  // 0..3
  const int bx = blockIdx.x;   // 1024
  const int b = bx >> 6;
  const int h = bx & 63;

  const float sfac = temperature[0] * 0.060112293370373475f;  // (1/24)*log2(e)
  const _Float16* wsp = ws;

  for (int d = tid; d < kD; d += 512) {
    int c = d / 9, r9 = d % 9, kh = r9 / 3, kw = r9 % 3;
    tab[d] = (c << 12) + (kh << 6) + kw + (kh << 20) + (kw << 24);
  }
  __syncthreads();

  // ---- build A-hi fragments (64 px = full w row) in fragment layout ----
  {
    const int base0 = (b * 4096 + (h - 1)) * 64 - 1;
    for (int i = 0; i < 9; ++i) {
      const int combo = i * 8 + wv;  // 0..71 = kt*4 + pt
      const int pt = combo & 3;
      const int kt = combo >> 2;
      const int pp = pt * 16 + l15;  // px = w
      const int dbase = kt * 32 + koct * 8;
      intx4 t0 = *reinterpret_cast<const intx4*>(&tab[dbase]);
      intx4 t1 = *reinterpret_cast<const intx4*>(&tab[dbase + 4]);
      half8 hv;
#pragma unroll
      for (int j = 0; j < 8; ++j) {
        int t = (j < 4) ? t0[j] : t1[j - 4];
        int off = t & 0xFFFFF;
        int kh = (t >> 20) & 15;
        int kw = (t >> 24) & 15;
        bool ok = ((unsigned)(h - 1 + kh) < 64u) && ((unsigned)(pp - 1 + kw) < 64u);
        int idx = ok ? (base0 + pp + off) : 0;
        float v = x[idx];
        v = ok ? v : 0.0f;
        hv[j] = (_Float16)v;
      }
      *reinterpret_cast<half8*>(&afrag[combo * 512 + lane * 8]) = hv;
    }
  }
  __syncthreads();  // A-frags visible to all waves

  const _Float16* abase = afrag + lane * 8;

  // ---- GEMM1 (2-term hi*(hi+lo)): wave owns m in [wv*64,+64), all 64 px ----
  // Full-kt pieces (8 loads: 4 mt x hi,lo), VGPR ring-3 (U,V,W), issue 2 ahead.
  floatx4 acc[4][4];  // [pt][mt]
  const floatx4 zed = {0.0f, 0.0f, 0.0f, 0.0f};
#pragma unroll
  for (int pt = 0; pt < 4; ++pt)
#pragma unroll
    for (int mt = 0; mt < 4; ++mt) acc[pt][mt] = zed;
  {
    int vb[4];
#pragma unroll
    for (int mt = 0; mt < 4; ++mt) vb[mt] = (wv * 64 + mt * 16 + l15) * 2304 + koct * 16;
    intx4 Uh0, Uh1, Uh2, Uh3, Ul0, Ul1, Ul2, Ul3;
    intx4 Vh0, Vh1, Vh2, Vh3, Vl0, Vl1, Vl2, Vl3;
    intx4 Wh0, Wh1, Wh2, Wh3, Wl0, Wl1, Wl2, Wl3;
    half8 aa0, aa1, aa2, aa3;
    int kti = 0;   // issue byte offset (kt*128)
    int aoff = 0;  // A-frag element offset (kt*2048)

#define G1_ISSUE(B)                 \
  do {                              \
    GLD16A(B##h0, vb[0] + kti, 0);  \
    GLD16A(B##l0, vb[0] + kti, 64); \
    GLD16A(B##h1, vb[1] + kti, 0);  \
    GLD16A(B##l1, vb[1] + kti, 64); \
    GLD16A(B##h2, vb[2] + kti, 0);  \
    GLD16A(B##l2, vb[2] + kti, 64); \
    GLD16A(B##h3, vb[3] + kti, 0);  \
    GLD16A(B##l3, vb[3] + kti, 64); \
    kti += 128;                     \
  } while (0)

#define G1_AREAD                                                   \
  do {                                                             \
    aa0 = *reinterpret_cast<const half8*>(abase + aoff);           \
    aa1 = *reinterpret_cast<const half8*>(abase + aoff + 512);     \
    aa2 = *reinterpret_cast<const half8*>(abase + aoff + 1024);    \
    aa3 = *reinterpret_cast<const half8*>(abase + aoff + 1536);    \
    aoff += 2048;                                                  \
  } while (0)

#define G1_MMA(B)                                    \
  do {                                               \
    __builtin_amdgcn_s_setprio(1);                   \
    acc[0][0] = MFMA16(aa0, asH8(B##h0), acc[0][0]); \
    acc[1][0] = MFMA16(aa1, asH8(B##h0), acc[1][0]); \
    acc[2][0] = MFMA16(aa2, asH8(B##h0), acc[2][0]); \
    acc[3][0] = MFMA16(aa3, asH8(B##h0), acc[3][0]); \
    acc[0][1] = MFMA16(aa0, asH8(B##h1), acc[0][1]); \
    acc[1][1] = MFMA16(aa1, asH8(B##h1), acc[1][1]); \
    acc[2][1] = MFMA16(aa2, asH8(B##h1), acc[2][1]); \
    acc[3][1] = MFMA16(aa3, asH8(B##h1), acc[3][1]); \
    acc[0][2] = MFMA16(aa0, asH8(B##h2), acc[0][2]); \
    acc[1][2] = MFMA16(aa1, asH8(B##h2), acc[1][2]); \
    acc[2][2] = MFMA16(aa2, asH8(B##h2), acc[2][2]); \
    acc[3][2] = MFMA16(aa3, asH8(B##h2), acc[3][2]); \
    acc[0][3] = MFMA16(aa0, asH8(B##h3), acc[0][3]); \
    acc[1][3] = MFMA16(aa1, asH8(B##h3), acc[1][3]); \
    acc[2][3] = MFMA16(aa2, asH8(B##h3), acc[2][3]); \
    acc[3][3] = MFMA16(aa3, asH8(B##h3), acc[3][3]); \
    acc[0][0] = MFMA16(aa0, asH8(B##l0), acc[0][0]); \
    acc[1][0] = MFMA16(aa1, asH8(B##l0), acc[1][0]); \
    acc[2][0] = MFMA16(aa2, asH8(B##l0), acc[2][0]); \
    acc[3][0] = MFMA16(aa3, asH8(B##l0), acc[3][0]); \
    acc[0][1] = MFMA16(aa0, asH8(B##l1), acc[0][1]); \
    acc[1][1] = MFMA16(aa1, asH8(B##l1), acc[1][1]); \
    acc[2][1] = MFMA16(aa2, asH8(B##l1), acc[2][1]); \
    acc[3][1] = MFMA16(aa3, asH8(B##l1), acc[3][1]); \
    acc[0][2] = MFMA16(aa0, asH8(B##l2), acc[0][2]); \
    acc[1][2] = MFMA16(aa1, asH8(B##l2), acc[1][2]); \
    acc[2][2] = MFMA16(aa2, asH8(B##l2), acc[2][2]); \
    acc[3][2] = MFMA16(aa3, asH8(B##l2), acc[3][2]); \
    acc[0][3] = MFMA16(aa0, asH8(B##l3), acc[0][3]); \
    acc[1][3] = MFMA16(aa1, asH8(B##l3), acc[1][3]); \
    acc[2][3] = MFMA16(aa2, asH8(B##l3), acc[2][3]); \
    acc[3][3] = MFMA16(aa3, asH8(B##l3), acc[3][3]); \
    __builtin_amdgcn_s_setprio(0);                   \
  } while (0)

#define G1_STEP(CUR, NXT, VMN) \
  do {                         \
    G1_ISSUE(NXT);             \
    G1_AREAD;                  \
    VMW(VMN);                  \
    G1_MMA(CUR);               \
  } while (0)

    G1_ISSUE(U);  // kt 0
    G1_ISSUE(V);  // kt 1
    for (int g = 0; g < 5; ++g) {  // kt = 3g..3g+2 (0..14), issues kt 2..16
      G1_STEP(U, W, 16);
      G1_STEP(V, U, 16);
      G1_STEP(W, V, 16);
    }
    G1_STEP(U, W, 16);  // kt 15, issues kt 17
    G1_AREAD;
    VMW(8);
    G1_MMA(V);  // kt 16
    G1_AREAD;
    VMW(0);
    G1_MMA(W);  // kt 17
  }

  // ---- softmax over m=512; lane: px = pt*16+koct*4+r, m = wv*64+mt*16+l15 ----
  float pm[4][4], ps[4][4];
#pragma unroll
  for (int pt = 0; pt < 4; ++pt)
#pragma unroll
    for (int r = 0; r < 4; ++r) {
      float v = acc[pt][0][r];
#pragma unroll
      for (int mt = 1; mt < 4; ++mt) v = fmaxf(v, acc[pt][mt][r]);
      pm[pt][r] = v;
    }
#pragma unroll
  for (int off = 1; off < 16; off <<= 1)
#pragma unroll
    for (int pt = 0; pt < 4; ++pt)
#pragma unroll
      for (int r = 0; r < 4; ++r) pm[pt][r] = fmaxf(pm[pt][r], __shfl_xor(pm[pt][r], off, 64));
  if (l15 == 0) {
#pragma unroll
    for (int pt = 0; pt < 4; ++pt)
#pragma unroll
      for (int r = 0; r < 4; ++r) redm[wv * 64 + pt * 16 + koct * 4 + r] = pm[pt][r];
  }
  __syncthreads();
#pragma unroll
  for (int pt = 0; pt < 4; ++pt)
#pragma unroll
    for (int r = 0; r < 4; ++r) {
      const int p = pt * 16 + koct * 4 + r;
      float g = redm[p];
#pragma unroll
      for (int w = 1; w < 8; ++w) g = fmaxf(g, redm[w * 64 + p]);
      pm[pt][r] = g;
      ps[pt][r] = 0.0f;
    }
#pragma unroll
  for (int pt = 0; pt < 4; ++pt)
#pragma unroll
    for (int mt = 0; mt < 4; ++mt)
#pragma unroll
      for (int r = 0; r < 4; ++r) {
        float e = exp2f((acc[pt][mt][r] - pm[pt][r]) * sfac);
        acc[pt][mt][r] = e;
        ps[pt][r] += e;
      }
#pragma unroll
  for (int off = 1; off < 16; off <<= 1)
#pragma unroll
    for (int pt = 0; pt < 4; ++pt)
#pragma unroll
      for (int r = 0; r < 4; ++r) ps[pt][r] += __shfl_xor(ps[pt][r], off, 64);
  if (l15 == 0) {
#pragma unroll
    for (int pt = 0; pt < 4; ++pt)
#pragma unroll
      for (int r = 0; r < 4; ++r) reds[wv * 64 + pt * 16 + koct * 4 + r] = ps[pt][r];
  }
  __syncthreads();
#pragma unroll
  for (int pt = 0; pt < 4; ++pt)
#pragma unroll
    for (int r = 0; r < 4; ++r) {
      const int p = pt * 16 + koct * 4 + r;
      float s = reds[p];
#pragma unroll
      for (int w = 1; w < 8; ++w) s += reds[w * 64 + p];
      ps[pt][r] = 1.0f / s;
    }
  // write att-hi fragments into afrag (A-frags dead: all waves past G1 via sync)
#pragma unroll
  for (int pt = 0; pt < 4; ++pt)
#pragma unroll
    for (int mt = 0; mt < 4; ++mt)
#pragma unroll
      for (int r = 0; r < 4; ++r) {
        float a = acc[pt][mt][r] * ps[pt][r];
        const int m = wv * 64 + mt * 16 + l15;
        const int idxe =
            (((m >> 5) * 4 + pt) * 64 + ((m >> 3) & 3) * 16 + koct * 4 + r) * 8 + (m & 7);
        afrag[idxe] = (_Float16)a;
      }
  __syncthreads();  // att-frags visible to all

  // ---- GEMM2 (hi-only): out[64][576] = att_hi @ mem_hi ----
  // wave owns 5 dtiles wv*5..wv*5+4 (tiles >=36 pad: clamped src, stores skipped).
  // Full-kt2 pieces (5 loads), VGPR ring-4 (Ta..Td), issue 3 ahead.
  floatx4 acc2[5][4];  // [nt][pt]
#pragma unroll
  for (int nt = 0; nt < 5; ++nt)
#pragma unroll
    for (int pt = 0; pt < 4; ++pt) acc2[nt][pt] = zed;
  {
    int vc[5];
#pragma unroll
    for (int nt = 0; nt < 5; ++nt) {
      int row = (wv * 5 + nt) * 16 + l15;
      if (row >= 576) row -= 576;  // pad rows clamp to valid data (discarded later)
      vc[nt] = WS2 * 2 + row * 1024 + koct * 16;
    }
    intx4 Ta0, Ta1, Ta2, Ta3, Ta4;
    intx4 Tb0, Tb1, Tb2, Tb3, Tb4;
    intx4 Tc0, Tc1, Tc2, Tc3, Tc4;
    intx4 Td0, Td1, Td2, Td3, Td4;
    half8 p0, p1, p2, p3;
    int kti2 = 0;   // issue byte offset (kt2*64)
    int aoff2 = 0;  // att-frag element offset (kt2*2048)

#define G2_ISSUE(B)                \
  do {                             \
    GLD16A(B##0, vc[0] + kti2, 0); \
    GLD16A(B##1, vc[1] + kti2, 0); \
    GLD16A(B##2, vc[2] + kti2, 0); \
    GLD16A(B##3, vc[3] + kti2, 0); \
    GLD16A(B##4, vc[4] + kti2, 0); \
    kti2 += 64;                    \
  } while (0)

#define G2_AREAD                                                  \
  do {                                                            \
    p0 = *reinterpret_cast<const half8*>(abase + aoff2);          \
    p1 = *reinterpret_cast<const half8*>(abase + aoff2 + 512);    \
    p2 = *reinterpret_cast<const half8*>(abase + aoff2 + 1024);   \
    p3 = *reinterpret_cast<const half8*>(abase + aoff2 + 1536);   \
    aoff2 += 2048;                                                \
  } while (0)

#define G2_MMA(B)                                   \
  do {                                              \
    __builtin_amdgcn_s_setprio(1);                  \
    acc2[0][0] = MFMA16(p0, asH8(B##0), acc2[0][0]); \
    acc2[0][1] = MFMA16(p1, asH8(B##0), acc2[0][1]); \
    acc2[0][2] = MFMA16(p2, asH8(B##0), acc2[0][2]); \
    acc2[0][3] = MFMA16(p3, asH8(B##0), acc2[0][3]); \
    acc2[1][0] = MFMA16(p0, asH8(B##1), acc2[1][0]); \
    acc2[1][1] = MFMA16(p1, asH8(B##1), acc2[1][1]); \
    acc2[1][2] = MFMA16(p2, asH8(B##1), acc2[1][2]); \
    acc2[1][3] = MFMA16(p3, asH8(B##1), acc2[1][3]); \
    acc2[2][0] = MFMA16(p0, asH8(B##2), acc2[2][0]); \
    acc2[2][1] = MFMA16(p1, asH8(B##2), acc2[2][1]); \
    acc2[2][2] = MFMA16(p2, asH8(B##2), acc2[2][2]); \
    acc2[2][3] = MFMA16(p3, asH8(B##2), acc2[2][3]); \
    acc2[3][0] = MFMA16(p0, asH8(B##3), acc2[3][0]); \
    acc2[3][1] = MFMA16(p1, asH8(B##3), acc2[3][1]); \
    acc2[3][2] = MFMA16(p2, asH8(B##3), acc2[3][2]); \
    acc2[3][3] = MFMA16(p3, asH8(B##3), acc2[3][3]); \
    acc2[4][0] = MFMA16(p0, asH8(B##4), acc2[4][0]); \
    acc2[4][1] = MFMA16(p1, asH8(B##4), acc2[4][1]); \
    acc2[4][2] = MFMA16(p2, asH8(B##4), acc2[4][2]); \
    acc2[4][3] = MFMA16(p3, asH8(B##4), acc2[4][3]); \
    __builtin_amdgcn_s_setprio(0);                  \
  } while (0)

#define G2_STEP(CUR, NXT, VMN) \
  do {                         \
    G2_ISSUE(NXT);             \
    G2_AREAD;                  \
    VMW(VMN);                  \
    G2_MMA(CUR);               \
  } while (0)

    G2_ISSUE(Ta);  // kt2 0
    G2_ISSUE(Tb);  // kt2 1
    G2_ISSUE(Tc);  // kt2 2
    for (int g = 0; g < 3; ++g) {  // kt2 = 4g..4g+3 (0..11), issues kt2 3..14
      G2_STEP(Ta, Td, 15);
      G2_STEP(Tb, Ta, 15);
      G2_STEP(Tc, Tb, 15);
      G2_STEP(Td, Tc, 15);
    }
    G2_STEP(Ta, Td, 15);  // kt2 12, issues kt2 15
    G2_AREAD;
    VMW(10);
    G2_MMA(Tb);  // kt2 13
    G2_AREAD;
    VMW(5);
    G2_MMA(Tc);  // kt2 14
    G2_AREAD;
    VMW(0);
    G2_MMA(Td);  // kt2 15
  }

  // ---- epilogue: nontemporal stores (skip pad tiles) ----
  {
    const int nbase = b * 4096 + h * 64;
#pragma unroll
    for (int nt = 0; nt < 5; ++nt) {
      const int dtile = wv * 5 + nt;
      if (dtile < 36) {
        const int d = dtile * 16 + l15;
#pragma unroll
        for (int pt = 0; pt < 4; ++pt)
#pragma unroll
          for (int r = 0; r < 4; ++r) {
            const int px = pt * 16 + koct * 4 + r;
            __builtin_nontemporal_store(acc2[nt][pt][r], &out[(nbase + px) * 576 + d]);
          }
      }
    }
  }
}

extern "C" void kernel_launch(void* const* d_in, const int* in_sizes, int n_in,
                              void* d_out, int out_size, void* d_ws, size_t ws_size,
                              hipStream_t stream) {
  const float* x = (const float*)d_in[0];
  const float* memory = (const float*)d_in[1];
  const float* temperature = (const float*)d_in[2];
  float* out = (float*)d_out;
  _Float16* ws = (_Float16*)d_ws;  // needs 1,769,472 bytes

  prep_split<<<512, 576, 0, stream>>>(memory, ws);
  mem_branch_kernel<<<1024, 512, 0, stream>>>(x, temperature, ws, out);
}

// Round 11
// 176.056 us; speedup vs baseline: 1.5227x; 1.5227x over previous
//
#include <hip/hip_runtime.h>

typedef _Float16 half8 __attribute__((ext_vector_type(8)));
typedef float floatx4 __attribute__((ext_vector_type(4)));
typedef int intx4 __attribute__((ext_vector_type(4)));

#define MFMA16(a, b, c) __builtin_amdgcn_mfma_f32_16x16x32_f16(a, b, c, 0, 0, 0)

static __device__ __forceinline__ half8 asH8(intx4 v) {
  half8 r;
  __builtin_memcpy(&r, &v, 16);
  return r;
}

static constexpr int kD = 576;
// ws layout (f16 elements), kt-major for per-lane coalesced B loads:
//   WS1H: [kt:18][m:512][32]  hi   elem = kt*16384 + m*32 + (d&31)
//   WS1L: [kt:18][m:512][32]  lo   (+294912)
//   WS2T: [kt2:16][d:576][32] hi   elem = WS2T + kt2*18432 + d*32 + (m&31)
static constexpr int WS1L = 294912;
static constexpr int WS2T = 589824;
// total ws: 884736 f16 = 1,769,472 bytes

__global__ void prep_split(const float* __restrict__ mem, _Float16* __restrict__ ws) {
  const int m = blockIdx.x;   // 512
  const int d = threadIdx.x;  // 576
  float v = mem[m * kD + d];
  _Float16 hi = (_Float16)v;
  _Float16 lo = (_Float16)(v - (float)hi);
  const int kt = d >> 5;
  ws[kt * 16384 + m * 32 + (d & 31)] = hi;
  ws[WS1L + kt * 16384 + m * 32 + (d & 31)] = lo;
  ws[WS2T + (m >> 5) * 18432 + d * 32 + (m & 31)] = hi;
}

// per-lane 16B global load to VGPR; wave-coalesced (1KB contiguous per instr)
#define GLD16A(dst, base, voff)                              \
  asm volatile("global_load_dwordx4 %0, %1, %2 offset:0"     \
               : "=v"(dst)                                   \
               : "v"(voff), "s"(base))
#define VMW(N)                                            \
  do {                                                    \
    asm volatile("s_waitcnt vmcnt(" #N ")" ::: "memory"); \
    __builtin_amdgcn_sched_barrier(0);                    \
  } while (0)

// One block: 64 pixels = one (b,h) row. 512 threads / 8 waves. 1 block/CU.
// Wave-decoupled: coalesced per-lane B loads into VGPR rings (G1 depth-3 of
// half-kt pieces, G2 depth-4), counted vmcnt, NO barriers inside GEMM loops.
__global__ __launch_bounds__(512, 2) void mem_branch_kernel(
    const float* __restrict__ x, const float* __restrict__ temperature,
    const _Float16* __restrict__ ws, float* __restrict__ out) {
  // A-frags (G1): [72 combos (kt*4+pt)][64 lanes][8 f16] = 73,728 B.
  // Reused for att-frags (G2): [64 combos (kt2*4+pt)][64][8] = 65,536 B.
  __shared__ __align__(16) _Float16 afrag[36864];
  __shared__ __align__(16) int tab[kD];
  __shared__ float redm[512];
  __shared__ float reds[512];

  const int tid = threadIdx.x;
  const int lane = tid & 63;
  const int wv = tid >> 6;  // 0..7
  const int l15 = lane & 15;
  const int koct = lane >> 4;  // 0..3
  const int bx = blockIdx.x;   // 1024
  const int b = bx >> 6;
  const int h = bx & 63;

  const float sfac = temperature[0] * 0.060112293370373475f;  // (1/24)*log2(e)
  const _Float16* wsp = ws;
  const _Float16* wspl = ws + WS1L;
  const _Float16* wsp2 = ws + WS2T;

  for (int d = tid; d < kD; d += 512) {
    int c = d / 9, r9 = d % 9, kh = r9 / 3, kw = r9 % 3;
    tab[d] = (c << 12) + (kh << 6) + kw + (kh << 20) + (kw << 24);
  }
  __syncthreads();

  // ---- build A-hi fragments (64 px = full w row) in fragment layout ----
  {
    const int base0 = (b * 4096 + (h - 1)) * 64 - 1;
    for (int i = 0; i < 9; ++i) {
      const int combo = i * 8 + wv;  // 0..71 = kt*4 + pt
      const int pt = combo & 3;
      const int kt = combo >> 2;
      const int pp = pt * 16 + l15;  // px = w
      const int dbase = kt * 32 + koct * 8;
      intx4 t0 = *reinterpret_cast<const intx4*>(&tab[dbase]);
      intx4 t1 = *reinterpret_cast<const intx4*>(&tab[dbase + 4]);
      half8 hv;
#pragma unroll
      for (int j = 0; j < 8; ++j) {
        int t = (j < 4) ? t0[j] : t1[j - 4];
        int off = t & 0xFFFFF;
        int kh = (t >> 20) & 15;
        int kw = (t >> 24) & 15;
        bool ok = ((unsigned)(h - 1 + kh) < 64u) && ((unsigned)(pp - 1 + kw) < 64u);
        int idx = ok ? (base0 + pp + off) : 0;
        float v = x[idx];
        v = ok ? v : 0.0f;
        hv[j] = (_Float16)v;
      }
      *reinterpret_cast<half8*>(&afrag[combo * 512 + lane * 8]) = hv;
    }
  }
  __syncthreads();  // A-frags visible to all waves

  const _Float16* abase = afrag + lane * 8;

  // ---- GEMM1 (2-term hi*(hi+lo)): wave owns m in [wv*64,+64), all 64 px ----
  // 36 half-kt pieces (4 coalesced loads each), ring-3 (U,V,W), issue 2 ahead.
  floatx4 acc[4][4];  // [pt][mt]
  const floatx4 zed = {0.0f, 0.0f, 0.0f, 0.0f};
#pragma unroll
  for (int pt = 0; pt < 4; ++pt)
#pragma unroll
    for (int mt = 0; mt < 4; ++mt) acc[pt][mt] = zed;
  {
    int vb[4];
#pragma unroll
    for (int mt = 0; mt < 4; ++mt) vb[mt] = (wv * 64 + mt * 16 + l15) * 64 + koct * 16;
    intx4 U0, U1, U2, U3, V0, V1, V2, V3, W0, W1, W2, W3;
    half8 aa0, aa1, aa2, aa3;
    int aoff = 0;

#define G1_ISSUE(B, BASE, KIO)        \
  do {                                \
    GLD16A(B##0, BASE, vb[0] + (KIO)); \
    GLD16A(B##1, BASE, vb[1] + (KIO)); \
    GLD16A(B##2, BASE, vb[2] + (KIO)); \
    GLD16A(B##3, BASE, vb[3] + (KIO)); \
  } while (0)

#define G1_AREAD                                                \
  do {                                                          \
    aa0 = *reinterpret_cast<const half8*>(abase + aoff);        \
    aa1 = *reinterpret_cast<const half8*>(abase + aoff + 512);  \
    aa2 = *reinterpret_cast<const half8*>(abase + aoff + 1024); \
    aa3 = *reinterpret_cast<const half8*>(abase + aoff + 1536); \
    aoff += 2048;                                               \
  } while (0)

#define G1_MMA(B)                                  \
  do {                                             \
    __builtin_amdgcn_s_setprio(1);                 \
    acc[0][0] = MFMA16(aa0, asH8(B##0), acc[0][0]); \
    acc[1][0] = MFMA16(aa1, asH8(B##0), acc[1][0]); \
    acc[2][0] = MFMA16(aa2, asH8(B##0), acc[2][0]); \
    acc[3][0] = MFMA16(aa3, asH8(B##0), acc[3][0]); \
    acc[0][1] = MFMA16(aa0, asH8(B##1), acc[0][1]); \
    acc[1][1] = MFMA16(aa1, asH8(B##1), acc[1][1]); \
    acc[2][1] = MFMA16(aa2, asH8(B##1), acc[2][1]); \
    acc[3][1] = MFMA16(aa3, asH8(B##1), acc[3][1]); \
    acc[0][2] = MFMA16(aa0, asH8(B##2), acc[0][2]); \
    acc[1][2] = MFMA16(aa1, asH8(B##2), acc[1][2]); \
    acc[2][2] = MFMA16(aa2, asH8(B##2), acc[2][2]); \
    acc[3][2] = MFMA16(aa3, asH8(B##2), acc[3][2]); \
    acc[0][3] = MFMA16(aa0, asH8(B##3), acc[0][3]); \
    acc[1][3] = MFMA16(aa1, asH8(B##3), acc[1][3]); \
    acc[2][3] = MFMA16(aa2, asH8(B##3), acc[2][3]); \
    acc[3][3] = MFMA16(aa3, asH8(B##3), acc[3][3]); \
    __builtin_amdgcn_s_setprio(0);                 \
  } while (0)

    // pieces p: kt=p>>1, half=p&1 (0=hi,1=lo); ring = p%3; kio = (p>>1)*32768
    G1_ISSUE(U, wsp, 0);   // p0 hi kt0
    G1_ISSUE(V, wspl, 0);  // p1 lo kt0
    for (int g = 0; g < 5; ++g) {  // pieces 6g..6g+5, issues 6g+2..6g+7
      const int k1 = (3 * g + 1) * 32768, k2 = k1 + 32768, k3 = k2 + 32768;
      G1_ISSUE(W, wsp, k1);  G1_AREAD; VMW(8); G1_MMA(U);
      G1_ISSUE(U, wspl, k1);           VMW(8); G1_MMA(V);
      G1_ISSUE(V, wsp, k2);  G1_AREAD; VMW(8); G1_MMA(W);
      G1_ISSUE(W, wspl, k2);           VMW(8); G1_MMA(U);
      G1_ISSUE(U, wsp, k3);  G1_AREAD; VMW(8); G1_MMA(V);
      G1_ISSUE(V, wspl, k3);           VMW(8); G1_MMA(W);
    }
    // tail: pieces 30..35 (kt 15,16,17), issues 32..35 (kt 16,17)
    {
      const int k16 = 16 * 32768, k17 = 17 * 32768;
      G1_ISSUE(W, wsp, k16);  G1_AREAD; VMW(8); G1_MMA(U);  // p30 hi kt15
      G1_ISSUE(U, wspl, k16);           VMW(8); G1_MMA(V);  // p31 lo kt15
      G1_ISSUE(V, wsp, k17);  G1_AREAD; VMW(8); G1_MMA(W);  // p32 hi kt16
      G1_ISSUE(W, wspl, k17);           VMW(8); G1_MMA(U);  // p33 lo kt16
      G1_AREAD; VMW(4); G1_MMA(V);                          // p34 hi kt17
      VMW(0); G1_MMA(W);                                    // p35 lo kt17
    }
  }

  // ---- softmax over m=512; lane: px = pt*16+koct*4+r, m = wv*64+mt*16+l15 ----
  float pm[4][4], ps[4][4];
#pragma unroll
  for (int pt = 0; pt < 4; ++pt)
#pragma unroll
    for (int r = 0; r < 4; ++r) {
      float v = acc[pt][0][r];
#pragma unroll
      for (int mt = 1; mt < 4; ++mt) v = fmaxf(v, acc[pt][mt][r]);
      pm[pt][r] = v;
    }
#pragma unroll
  for (int off = 1; off < 16; off <<= 1)
#pragma unroll
    for (int pt = 0; pt < 4; ++pt)
#pragma unroll
      for (int r = 0; r < 4; ++r) pm[pt][r] = fmaxf(pm[pt][r], __shfl_xor(pm[pt][r], off, 64));
  if (l15 == 0) {
#pragma unroll
    for (int pt = 0; pt < 4; ++pt)
#pragma unroll
      for (int r = 0; r < 4; ++r) redm[wv * 64 + pt * 16 + koct * 4 + r] = pm[pt][r];
  }
  __syncthreads();
#pragma unroll
  for (int pt = 0; pt < 4; ++pt)
#pragma unroll
    for (int r = 0; r < 4; ++r) {
      const int p = pt * 16 + koct * 4 + r;
      float g = redm[p];
#pragma unroll
      for (int w = 1; w < 8; ++w) g = fmaxf(g, redm[w * 64 + p]);
      pm[pt][r] = g;
      ps[pt][r] = 0.0f;
    }
#pragma unroll
  for (int pt = 0; pt < 4; ++pt)
#pragma unroll
    for (int mt = 0; mt < 4; ++mt)
#pragma unroll
      for (int r = 0; r < 4; ++r) {
        float e = exp2f((acc[pt][mt][r] - pm[pt][r]) * sfac);
        acc[pt][mt][r] = e;
        ps[pt][r] += e;
      }
#pragma unroll
  for (int off = 1; off < 16; off <<= 1)
#pragma unroll
    for (int pt = 0; pt < 4; ++pt)
#pragma unroll
      for (int r = 0; r < 4; ++r) ps[pt][r] += __shfl_xor(ps[pt][r], off, 64);
  if (l15 == 0) {
#pragma unroll
    for (int pt = 0; pt < 4; ++pt)
#pragma unroll
      for (int r = 0; r < 4; ++r) reds[wv * 64 + pt * 16 + koct * 4 + r] = ps[pt][r];
  }
  __syncthreads();
#pragma unroll
  for (int pt = 0; pt < 4; ++pt)
#pragma unroll
    for (int r = 0; r < 4; ++r) {
      const int p = pt * 16 + koct * 4 + r;
      float s = reds[p];
#pragma unroll
      for (int w = 1; w < 8; ++w) s += reds[w * 64 + p];
      ps[pt][r] = 1.0f / s;
    }
  // write att-hi fragments into afrag (A-frags dead: all waves past G1 via sync)
#pragma unroll
  for (int pt = 0; pt < 4; ++pt)
#pragma unroll
    for (int mt = 0; mt < 4; ++mt)
#pragma unroll
      for (int r = 0; r < 4; ++r) {
        float a = acc[pt][mt][r] * ps[pt][r];
        const int m = wv * 64 + mt * 16 + l15;
        const int idxe =
            (((m >> 5) * 4 + pt) * 64 + ((m >> 3) & 3) * 16 + koct * 4 + r) * 8 + (m & 7);
        afrag[idxe] = (_Float16)a;
      }
  __syncthreads();  // att-frags visible to all

  // ---- GEMM2 (hi-only): out[64][576] = att_hi @ mem_hi ----
  // wave owns 5 dtiles wv*5..wv*5+4 (tiles >=36 pad: clamped src, stores skipped).
  // 16 full-kt2 pieces (5 coalesced loads), ring-4 (Ta..Td), issue 3 ahead.
  floatx4 acc2[5][4];  // [nt][pt]
#pragma unroll
  for (int nt = 0; nt < 5; ++nt)
#pragma unroll
    for (int pt = 0; pt < 4; ++pt) acc2[nt][pt] = zed;
  {
    int vc[5];
#pragma unroll
    for (int nt = 0; nt < 5; ++nt) {
      int row = (wv * 5 + nt) * 16 + l15;
      if (row >= 576) row -= 576;  // pad rows clamp to valid data (discarded later)
      vc[nt] = row * 64 + koct * 16;
    }
    intx4 Ta0, Ta1, Ta2, Ta3, Ta4;
    intx4 Tb0, Tb1, Tb2, Tb3, Tb4;
    intx4 Tc0, Tc1, Tc2, Tc3, Tc4;
    intx4 Td0, Td1, Td2, Td3, Td4;
    half8 p0, p1, p2, p3;
    int aoff2 = 0;

#define G2_ISSUE(B, KIO)               \
  do {                                 \
    GLD16A(B##0, wsp2, vc[0] + (KIO)); \
    GLD16A(B##1, wsp2, vc[1] + (KIO)); \
    GLD16A(B##2, wsp2, vc[2] + (KIO)); \
    GLD16A(B##3, wsp2, vc[3] + (KIO)); \
    GLD16A(B##4, wsp2, vc[4] + (KIO)); \
  } while (0)

#define G2_AREAD                                                 \
  do {                                                           \
    p0 = *reinterpret_cast<const half8*>(abase + aoff2);         \
    p1 = *reinterpret_cast<const half8*>(abase + aoff2 + 512);   \
    p2 = *reinterpret_cast<const half8*>(abase + aoff2 + 1024);  \
    p3 = *reinterpret_cast<const half8*>(abase + aoff2 + 1536);  \
    aoff2 += 2048;                                               \
  } while (0)

#define G2_MMA(B)                                    \
  do {                                               \
    __builtin_amdgcn_s_setprio(1);                   \
    acc2[0][0] = MFMA16(p0, asH8(B##0), acc2[0][0]); \
    acc2[0][1] = MFMA16(p1, asH8(B##0), acc2[0][1]); \
    acc2[0][2] = MFMA16(p2, asH8(B##0), acc2[0][2]); \
    acc2[0][3] = MFMA16(p3, asH8(B##0), acc2[0][3]); \
    acc2[1][0] = MFMA16(p0, asH8(B##1), acc2[1][0]); \
    acc2[1][1] = MFMA16(p1, asH8(B##1), acc2[1][1]); \
    acc2[1][2] = MFMA16(p2, asH8(B##1), acc2[1][2]); \
    acc2[1][3] = MFMA16(p3, asH8(B##1), acc2[1][3]); \
    acc2[2][0] = MFMA16(p0, asH8(B##2), acc2[2][0]); \
    acc2[2][1] = MFMA16(p1, asH8(B##2), acc2[2][1]); \
    acc2[2][2] = MFMA16(p2, asH8(B##2), acc2[2][2]); \
    acc2[2][3] = MFMA16(p3, asH8(B##2), acc2[2][3]); \
    acc2[3][0] = MFMA16(p0, asH8(B##3), acc2[3][0]); \
    acc2[3][1] = MFMA16(p1, asH8(B##3), acc2[3][1]); \
    acc2[3][2] = MFMA16(p2, asH8(B##3), acc2[3][2]); \
    acc2[3][3] = MFMA16(p3, asH8(B##3), acc2[3][3]); \
    acc2[4][0] = MFMA16(p0, asH8(B##4), acc2[4][0]); \
    acc2[4][1] = MFMA16(p1, asH8(B##4), acc2[4][1]); \
    acc2[4][2] = MFMA16(p2, asH8(B##4), acc2[4][2]); \
    acc2[4][3] = MFMA16(p3, asH8(B##4), acc2[4][3]); \
    __builtin_amdgcn_s_setprio(0);                   \
  } while (0)

    // pieces p: kt2 = p; ring = p%4; kio = p*36864
    G2_ISSUE(Ta, 0);
    G2_ISSUE(Tb, 36864);
    G2_ISSUE(Tc, 73728);
    for (int g = 0; g < 3; ++g) {  // pieces 4g..4g+3, issues 4g+3..4g+6
      const int j3 = (4 * g + 3) * 36864, j4 = j3 + 36864, j5 = j4 + 36864, j6 = j5 + 36864;
      G2_ISSUE(Td, j3); G2_AREAD; VMW(15); G2_MMA(Ta);
      G2_ISSUE(Ta, j4); G2_AREAD; VMW(15); G2_MMA(Tb);
      G2_ISSUE(Tb, j5); G2_AREAD; VMW(15); G2_MMA(Tc);
      G2_ISSUE(Tc, j6); G2_AREAD; VMW(15); G2_MMA(Td);
    }
    // tail: pieces 12..15, one remaining issue (15)
    G2_ISSUE(Td, 15 * 36864); G2_AREAD; VMW(15); G2_MMA(Ta);  // p12
    G2_AREAD; VMW(10); G2_MMA(Tb);                            // p13
    G2_AREAD; VMW(5);  G2_MMA(Tc);                            // p14
    G2_AREAD; VMW(0);  G2_MMA(Td);                            // p15
  }

  // ---- epilogue: nontemporal stores (skip pad tiles) ----
  {
    const int nbase = b * 4096 + h * 64;
#pragma unroll
    for (int nt = 0; nt < 5; ++nt) {
      const int dtile = wv * 5 + nt;
      if (dtile < 36) {
        const int d = dtile * 16 + l15;
#pragma unroll
        for (int pt = 0; pt < 4; ++pt)
#pragma unroll
          for (int r = 0; r < 4; ++r) {
            const int px = pt * 16 + koct * 4 + r;
            __builtin_nontemporal_store(acc2[nt][pt][r], &out[(nbase + px) * 576 + d]);
          }
      }
    }
  }
}

extern "C" void kernel_launch(void* const* d_in, const int* in_sizes, int n_in,
                              void* d_out, int out_size, void* d_ws, size_t ws_size,
                              hipStream_t stream) {
  const float* x = (const float*)d_in[0];
  const float* memory = (const float*)d_in[1];
  const float* temperature = (const float*)d_in[2];
  float* out = (float*)d_out;
  _Float16* ws = (_Float16*)d_ws;  // needs 1,769,472 bytes

  prep_split<<<512, 576, 0, stream>>>(memory, ws);
  mem_branch_kernel<<<1024, 512, 0, stream>>>(x, temperature, ws, out);
}

// Round 13
// 175.554 us; speedup vs baseline: 1.5271x; 1.0029x over previous
//
#include <hip/hip_runtime.h>

typedef _Float16 half8 __attribute__((ext_vector_type(8)));
typedef float floatx4 __attribute__((ext_vector_type(4)));
typedef int intx4 __attribute__((ext_vector_type(4)));

#define MFMA16(a, b, c) __builtin_amdgcn_mfma_f32_16x16x32_f16(a, b, c, 0, 0, 0)

static __device__ __forceinline__ half8 asH8(intx4 v) {
  half8 r;
  __builtin_memcpy(&r, &v, 16);
  return r;
}

static constexpr int kD = 576;
// ws layout (f16 elements), kt-major for per-lane coalesced B loads:
//   WS1H: [kt:18][m:512][32]  hi   elem = kt*16384 + m*32 + (d&31)
//   WS1L: [kt:18][m:512][32]  lo   (+294912)
//   WS2T: [kt2:16][d:576][32] hi   elem = WS2T + kt2*18432 + d*32 + (m&31)
static constexpr int WS1L = 294912;
static constexpr int WS2T = 589824;
// total ws: 884736 f16 = 1,769,472 bytes

__global__ void prep_split(const float* __restrict__ mem, _Float16* __restrict__ ws) {
  const int m = blockIdx.x;   // 512
  const int d = threadIdx.x;  // 576
  float v = mem[m * kD + d];
  _Float16 hi = (_Float16)v;
  _Float16 lo = (_Float16)(v - (float)hi);
  const int kt = d >> 5;
  ws[kt * 16384 + m * 32 + (d & 31)] = hi;
  ws[WS1L + kt * 16384 + m * 32 + (d & 31)] = lo;
  ws[WS2T + (m >> 5) * 18432 + d * 32 + (m & 31)] = hi;
}

// per-lane 16B global load to VGPR; wave-coalesced (1KB contiguous per instr)
#define GLD16A(dst, base, voff)                              \
  asm volatile("global_load_dwordx4 %0, %1, %2 offset:0"     \
               : "=v"(dst)                                   \
               : "v"(voff), "s"(base))
#define VMW(N)                                            \
  do {                                                    \
    asm volatile("s_waitcnt vmcnt(" #N ")" ::: "memory"); \
    __builtin_amdgcn_sched_barrier(0);                    \
  } while (0)

// One block: 64 pixels = one (b,h) row. 512 threads / 8 waves.
// LDS 77824B (x2 = 155648 <= 163840 -> 2 blocks/CU target). Wave-decoupled:
// coalesced per-lane B loads into VGPR rings, counted vmcnt, NO barriers
// inside GEMM loops.
__global__ __launch_bounds__(512, 2) void mem_branch_kernel(
    const float* __restrict__ x, const float* __restrict__ temperature,
    const _Float16* __restrict__ ws, float* __restrict__ out) {
  // blob (77824 B):
  //  [0,73728)        A-frags (G1) -> att-frags (G2, 65536 used)
  //  [73728,77824)    union{ tab[576] int (A-build only, pre-G1) |
  //                          redm[512]+reds[512] float (softmax, post-G1) }
  __shared__ __align__(16) unsigned char blob[77824];
  _Float16* afrag = (_Float16*)blob;
  int* tab = (int*)(blob + 73728);
  float* redm = (float*)(blob + 73728);
  float* reds = (float*)(blob + 73728 + 2048);

  const int tid = threadIdx.x;
  const int lane = tid & 63;
  const int wv = tid >> 6;  // 0..7
  const int l15 = lane & 15;
  const int koct = lane >> 4;  // 0..3
  const int bx = blockIdx.x;   // 1024
  const int b = bx >> 6;
  const int h = bx & 63;

  const float sfac = temperature[0] * 0.060112293370373475f;  // (1/24)*log2(e)
  const _Float16* wsp = ws;
  const _Float16* wspl = ws + WS1L;
  const _Float16* wsp2 = ws + WS2T;

  for (int d = tid; d < kD; d += 512) {
    int c = d / 9, r9 = d % 9, kh = r9 / 3, kw = r9 % 3;
    tab[d] = (c << 12) + (kh << 6) + kw + (kh << 20) + (kw << 24);
  }
  __syncthreads();

  // ---- build A-hi fragments (64 px = full w row) in fragment layout ----
  {
    const int base0 = (b * 4096 + (h - 1)) * 64 - 1;
    for (int i = 0; i < 9; ++i) {
      const int combo = i * 8 + wv;  // 0..71 = kt*4 + pt
      const int pt = combo & 3;
      const int kt = combo >> 2;
      const int pp = pt * 16 + l15;  // px = w
      const int dbase = kt * 32 + koct * 8;
      intx4 t0 = *reinterpret_cast<const intx4*>(&tab[dbase]);
      intx4 t1 = *reinterpret_cast<const intx4*>(&tab[dbase + 4]);
      half8 hv;
#pragma unroll
      for (int j = 0; j < 8; ++j) {
        int t = (j < 4) ? t0[j] : t1[j - 4];
        int off = t & 0xFFFFF;
        int kh = (t >> 20) & 15;
        int kw = (t >> 24) & 15;
        bool ok = ((unsigned)(h - 1 + kh) < 64u) && ((unsigned)(pp - 1 + kw) < 64u);
        int idx = ok ? (base0 + pp + off) : 0;
        float v = x[idx];
        v = ok ? v : 0.0f;
        hv[j] = (_Float16)v;
      }
      *reinterpret_cast<half8*>(&afrag[combo * 512 + lane * 8]) = hv;
    }
  }
  __syncthreads();  // A-frags visible; tab dead -> redm/reds region free

  const _Float16* abase = afrag + lane * 8;

  // ---- GEMM1 (2-term hi*(hi+lo)): wave owns m in [wv*64,+64), all 64 px ----
  // 36 half-kt pieces (4 coalesced loads each), ring-3 (U,V,W), issue 2 ahead.
  floatx4 acc[4][4];  // [pt][mt]
  const floatx4 zed = {0.0f, 0.0f, 0.0f, 0.0f};
#pragma unroll
  for (int pt = 0; pt < 4; ++pt)
#pragma unroll
    for (int mt = 0; mt < 4; ++mt) acc[pt][mt] = zed;
  {
    int vb[4];
#pragma unroll
    for (int mt = 0; mt < 4; ++mt) vb[mt] = (wv * 64 + mt * 16 + l15) * 64 + koct * 16;
    intx4 U0, U1, U2, U3, V0, V1, V2, V3, W0, W1, W2, W3;
    half8 aa0, aa1, aa2, aa3;
    int aoff = 0;

#define G1_ISSUE(B, BASE, KIO)        \
  do {                                \
    GLD16A(B##0, BASE, vb[0] + (KIO)); \
    GLD16A(B##1, BASE, vb[1] + (KIO)); \
    GLD16A(B##2, BASE, vb[2] + (KIO)); \
    GLD16A(B##3, BASE, vb[3] + (KIO)); \
  } while (0)

#define G1_AREAD                                                \
  do {                                                          \
    aa0 = *reinterpret_cast<const half8*>(abase + aoff);        \
    aa1 = *reinterpret_cast<const half8*>(abase + aoff + 512);  \
    aa2 = *reinterpret_cast<const half8*>(abase + aoff + 1024); \
    aa3 = *reinterpret_cast<const half8*>(abase + aoff + 1536); \
    aoff += 2048;                                               \
  } while (0)

#define G1_MMA(B)                                  \
  do {                                             \
    __builtin_amdgcn_s_setprio(1);                 \
    acc[0][0] = MFMA16(aa0, asH8(B##0), acc[0][0]); \
    acc[1][0] = MFMA16(aa1, asH8(B##0), acc[1][0]); \
    acc[2][0] = MFMA16(aa2, asH8(B##0), acc[2][0]); \
    acc[3][0] = MFMA16(aa3, asH8(B##0), acc[3][0]); \
    acc[0][1] = MFMA16(aa0, asH8(B##1), acc[0][1]); \
    acc[1][1] = MFMA16(aa1, asH8(B##1), acc[1][1]); \
    acc[2][1] = MFMA16(aa2, asH8(B##1), acc[2][1]); \
    acc[3][1] = MFMA16(aa3, asH8(B##1), acc[3][1]); \
    acc[0][2] = MFMA16(aa0, asH8(B##2), acc[0][2]); \
    acc[1][2] = MFMA16(aa1, asH8(B##2), acc[1][2]); \
    acc[2][2] = MFMA16(aa2, asH8(B##2), acc[2][2]); \
    acc[3][2] = MFMA16(aa3, asH8(B##2), acc[3][2]); \
    acc[0][3] = MFMA16(aa0, asH8(B##3), acc[0][3]); \
    acc[1][3] = MFMA16(aa1, asH8(B##3), acc[1][3]); \
    acc[2][3] = MFMA16(aa2, asH8(B##3), acc[2][3]); \
    acc[3][3] = MFMA16(aa3, asH8(B##3), acc[3][3]); \
    __builtin_amdgcn_s_setprio(0);                 \
  } while (0)

    // pieces p: kt=p>>1, half=p&1 (0=hi,1=lo); ring = p%3; kio = (p>>1)*32768
    G1_ISSUE(U, wsp, 0);   // p0 hi kt0
    G1_ISSUE(V, wspl, 0);  // p1 lo kt0
    for (int g = 0; g < 5; ++g) {  // pieces 6g..6g+5, issues 6g+2..6g+7
      const int k1 = (3 * g + 1) * 32768, k2 = k1 + 32768, k3 = k2 + 32768;
      G1_ISSUE(W, wsp, k1);  G1_AREAD; VMW(8); G1_MMA(U);
      G1_ISSUE(U, wspl, k1);           VMW(8); G1_MMA(V);
      G1_ISSUE(V, wsp, k2);  G1_AREAD; VMW(8); G1_MMA(W);
      G1_ISSUE(W, wspl, k2);           VMW(8); G1_MMA(U);
      G1_ISSUE(U, wsp, k3);  G1_AREAD; VMW(8); G1_MMA(V);
      G1_ISSUE(V, wspl, k3);           VMW(8); G1_MMA(W);
    }
    // tail: pieces 30..35 (kt 15,16,17), issues 32..35 (kt 16,17)
    {
      const int k16 = 16 * 32768, k17 = 17 * 32768;
      G1_ISSUE(W, wsp, k16);  G1_AREAD; VMW(8); G1_MMA(U);  // p30 hi kt15
      G1_ISSUE(U, wspl, k16);           VMW(8); G1_MMA(V);  // p31 lo kt15
      G1_ISSUE(V, wsp, k17);  G1_AREAD; VMW(8); G1_MMA(W);  // p32 hi kt16
      G1_ISSUE(W, wspl, k17);           VMW(8); G1_MMA(U);  // p33 lo kt16
      G1_AREAD; VMW(4); G1_MMA(V);                          // p34 hi kt17
      VMW(0); G1_MMA(W);                                    // p35 lo kt17
    }
  }

  // ---- softmax over m=512; lane: px = pt*16+koct*4+r, m = wv*64+mt*16+l15 ----
  float pm[4][4], ps[4][4];
#pragma unroll
  for (int pt = 0; pt < 4; ++pt)
#pragma unroll
    for (int r = 0; r < 4; ++r) {
      float v = acc[pt][0][r];
#pragma unroll
      for (int mt = 1; mt < 4; ++mt) v = fmaxf(v, acc[pt][mt][r]);
      pm[pt][r] = v;
    }
#pragma unroll
  for (int off = 1; off < 16; off <<= 1)
#pragma unroll
    for (int pt = 0; pt < 4; ++pt)
#pragma unroll
      for (int r = 0; r < 4; ++r) pm[pt][r] = fmaxf(pm[pt][r], __shfl_xor(pm[pt][r], off, 64));
  if (l15 == 0) {
#pragma unroll
    for (int pt = 0; pt < 4; ++pt)
#pragma unroll
      for (int r = 0; r < 4; ++r) redm[wv * 64 + pt * 16 + koct * 4 + r] = pm[pt][r];
  }
  __syncthreads();
#pragma unroll
  for (int pt = 0; pt < 4; ++pt)
#pragma unroll
    for (int r = 0; r < 4; ++r) {
      const int p = pt * 16 + koct * 4 + r;
      float g = redm[p];
#pragma unroll
      for (int w = 1; w < 8; ++w) g = fmaxf(g, redm[w * 64 + p]);
      pm[pt][r] = g;
      ps[pt][r] = 0.0f;
    }
#pragma unroll
  for (int pt = 0; pt < 4; ++pt)
#pragma unroll
    for (int mt = 0; mt < 4; ++mt)
#pragma unroll
      for (int r = 0; r < 4; ++r) {
        float e = exp2f((acc[pt][mt][r] - pm[pt][r]) * sfac);
        acc[pt][mt][r] = e;
        ps[pt][r] += e;
      }
#pragma unroll
  for (int off = 1; off < 16; off <<= 1)
#pragma unroll
    for (int pt = 0; pt < 4; ++pt)
#pragma unroll
      for (int r = 0; r < 4; ++r) ps[pt][r] += __shfl_xor(ps[pt][r], off, 64);
  if (l15 == 0) {
#pragma unroll
    for (int pt = 0; pt < 4; ++pt)
#pragma unroll
      for (int r = 0; r < 4; ++r) reds[wv * 64 + pt * 16 + koct * 4 + r] = ps[pt][r];
  }
  __syncthreads();
#pragma unroll
  for (int pt = 0; pt < 4; ++pt)
#pragma unroll
    for (int r = 0; r < 4; ++r) {
      const int p = pt * 16 + koct * 4 + r;
      float s = reds[p];
#pragma unroll
      for (int w = 1; w < 8; ++w) s += reds[w * 64 + p];
      ps[pt][r] = 1.0f / s;
    }
  // write att-hi fragments into afrag (A-frags dead: all waves past G1 via sync)
#pragma unroll
  for (int pt = 0; pt < 4; ++pt)
#pragma unroll
    for (int mt = 0; mt < 4; ++mt)
#pragma unroll
      for (int r = 0; r < 4; ++r) {
        float a = acc[pt][mt][r] * ps[pt][r];
        const int m = wv * 64 + mt * 16 + l15;
        const int idxe =
            (((m >> 5) * 4 + pt) * 64 + ((m >> 3) & 3) * 16 + koct * 4 + r) * 8 + (m & 7);
        afrag[idxe] = (_Float16)a;
      }
  __syncthreads();  // att-frags visible to all

  // ---- GEMM2 (hi-only): out[64][576] = att_hi @ mem_hi ----
  // wave owns 5 dtiles wv*5..wv*5+4 (tiles >=36 pad: clamped src, stores skipped).
  // 16 full-kt2 pieces (5 coalesced loads), ring-4 (Ta..Td), issue 3 ahead.
  floatx4 acc2[5][4];  // [nt][pt]
#pragma unroll
  for (int nt = 0; nt < 5; ++nt)
#pragma unroll
    for (int pt = 0; pt < 4; ++pt) acc2[nt][pt] = zed;
  {
    int vc[5];
#pragma unroll
    for (int nt = 0; nt < 5; ++nt) {
      int row = (wv * 5 + nt) * 16 + l15;
      if (row >= 576) row -= 576;  // pad rows clamp to valid data (discarded later)
      vc[nt] = row * 64 + koct * 16;
    }
    intx4 Ta0, Ta1, Ta2, Ta3, Ta4;
    intx4 Tb0, Tb1, Tb2, Tb3, Tb4;
    intx4 Tc0, Tc1, Tc2, Tc3, Tc4;
    intx4 Td0, Td1, Td2, Td3, Td4;
    half8 p0, p1, p2, p3;
    int aoff2 = 0;

#define G2_ISSUE(B, KIO)               \
  do {                                 \
    GLD16A(B##0, wsp2, vc[0] + (KIO)); \
    GLD16A(B##1, wsp2, vc[1] + (KIO)); \
    GLD16A(B##2, wsp2, vc[2] + (KIO)); \
    GLD16A(B##3, wsp2, vc[3] + (KIO)); \
    GLD16A(B##4, wsp2, vc[4] + (KIO)); \
  } while (0)

#define G2_AREAD                                                 \
  do {                                                           \
    p0 = *reinterpret_cast<const half8*>(abase + aoff2);         \
    p1 = *reinterpret_cast<const half8*>(abase + aoff2 + 512);   \
    p2 = *reinterpret_cast<const half8*>(abase + aoff2 + 1024);  \
    p3 = *reinterpret_cast<const half8*>(abase + aoff2 + 1536);  \
    aoff2 += 2048;                                               \
  } while (0)

#define G2_MMA(B)                                    \
  do {                                               \
    __builtin_amdgcn_s_setprio(1);                   \
    acc2[0][0] = MFMA16(p0, asH8(B##0), acc2[0][0]); \
    acc2[0][1] = MFMA16(p1, asH8(B##0), acc2[0][1]); \
    acc2[0][2] = MFMA16(p2, asH8(B##0), acc2[0][2]); \
    acc2[0][3] = MFMA16(p3, asH8(B##0), acc2[0][3]); \
    acc2[1][0] = MFMA16(p0, asH8(B##1), acc2[1][0]); \
    acc2[1][1] = MFMA16(p1, asH8(B##1), acc2[1][1]); \
    acc2[1][2] = MFMA16(p2, asH8(B##1), acc2[1][2]); \
    acc2[1][3] = MFMA16(p3, asH8(B##1), acc2[1][3]); \
    acc2[2][0] = MFMA16(p0, asH8(B##2), acc2[2][0]); \
    acc2[2][1] = MFMA16(p1, asH8(B##2), acc2[2][1]); \
    acc2[2][2] = MFMA16(p2, asH8(B##2), acc2[2][2]); \
    acc2[2][3] = MFMA16(p3, asH8(B##2), acc2[2][3]); \
    acc2[3][0] = MFMA16(p0, asH8(B##3), acc2[3][0]); \
    acc2[3][1] = MFMA16(p1, asH8(B##3), acc2[3][1]); \
    acc2[3][2] = MFMA16(p2, asH8(B##3), acc2[3][2]); \
    acc2[3][3] = MFMA16(p3, asH8(B##3), acc2[3][3]); \
    acc2[4][0] = MFMA16(p0, asH8(B##4), acc2[4][0]); \
    acc2[4][1] = MFMA16(p1, asH8(B##4), acc2[4][1]); \
    acc2[4][2] = MFMA16(p2, asH8(B##4), acc2[4][2]); \
    acc2[4][3] = MFMA16(p3, asH8(B##4), acc2[4][3]); \
    __builtin_amdgcn_s_setprio(0);                   \
  } while (0)

    // pieces p: kt2 = p; ring = p%4; kio = p*36864
    G2_ISSUE(Ta, 0);
    G2_ISSUE(Tb, 36864);
    G2_ISSUE(Tc, 73728);
    for (int g = 0; g < 3; ++g) {  // pieces 4g..4g+3, issues 4g+3..4g+6
      const int j3 = (4 * g + 3) * 36864, j4 = j3 + 36864, j5 = j4 + 36864, j6 = j5 + 36864;
      G2_ISSUE(Td, j3); G2_AREAD; VMW(15); G2_MMA(Ta);
      G2_ISSUE(Ta, j4); G2_AREAD; VMW(15); G2_MMA(Tb);
      G2_ISSUE(Tb, j5); G2_AREAD; VMW(15); G2_MMA(Tc);
      G2_ISSUE(Tc, j6); G2_AREAD; VMW(15); G2_MMA(Td);
    }
    // tail: pieces 12..15, one remaining issue (15)
    G2_ISSUE(Td, 15 * 36864); G2_AREAD; VMW(15); G2_MMA(Ta);  // p12
    G2_AREAD; VMW(10); G2_MMA(Tb);                            // p13
    G2_AREAD; VMW(5);  G2_MMA(Tc);                            // p14
    G2_AREAD; VMW(0);  G2_MMA(Td);                            // p15
  }

  // ---- epilogue: nontemporal stores (skip pad tiles) ----
  {
    const int nbase = b * 4096 + h * 64;
#pragma unroll
    for (int nt = 0; nt < 5; ++nt) {
      const int dtile = wv * 5 + nt;
      if (dtile < 36) {
        const int d = dtile * 16 + l15;
#pragma unroll
        for (int pt = 0; pt < 4; ++pt)
#pragma unroll
          for (int r = 0; r < 4; ++r) {
            const int px = pt * 16 + koct * 4 + r;
            __builtin_nontemporal_store(acc2[nt][pt][r], &out[(nbase + px) * 576 + d]);
          }
      }
    }
  }
}

extern "C" void kernel_launch(void* const* d_in, const int* in_sizes, int n_in,
                              void* d_out, int out_size, void* d_ws, size_t ws_size,
                              hipStream_t stream) {
  const float* x = (const float*)d_in[0];
  const float* memory = (const float*)d_in[1];
  const float* temperature = (const float*)d_in[2];
  float* out = (float*)d_out;
  _Float16* ws = (_Float16*)d_ws;  // needs 1,769,472 bytes

  prep_split<<<512, 576, 0, stream>>>(memory, ws);
  mem_branch_kernel<<<1024, 512, 0, stream>>>(x, temperature, ws, out);
}